// Round 11
// baseline (407.175 us; speedup 1.0000x reference)
//
#include <hip/hip_runtime.h>
#include <cstddef>
#include <cstdint>

constexpr int kC = 192;    // channels
constexpr int kW = 512;    // sequence length
constexpr int kHH = 48;    // H

typedef unsigned short u16;
typedef __attribute__((ext_vector_type(8))) short bf16x8;
typedef __attribute__((ext_vector_type(4))) float f32x4;
typedef __attribute__((ext_vector_type(4))) unsigned short us4;

__device__ inline u16 f2bf(float f) {
  union { float f; uint32_t u; } v; v.f = f;
  uint32_t r = v.u + 0x7FFF + ((v.u >> 16) & 1);  // RNE
  return (u16)(r >> 16);
}
__device__ inline float bf2f(u16 u) {
  return __uint_as_float(((uint32_t)u) << 16);
}

// ---------------- prep: LayerNorm (blocks 0..1535) + weight conversion (rest) ---------
__global__ void __launch_bounds__(256) prep_kernel(
    const float* __restrict__ xl, const float* __restrict__ xr,
    const float* __restrict__ gl, const float* __restrict__ bl,
    const float* __restrict__ gr, const float* __restrict__ br,
    u16* __restrict__ lnl, u16* __restrict__ lraw,
    u16* __restrict__ lnr, u16* __restrict__ rraw,
    const float* wq0, const float* wk0, const float* wv0,
    const float* wq1, const float* wk1, const float* wv1,
    const float* bq0, const float* bk0, const float* bv0,
    const float* bq1, const float* bk1, const float* bv1,
    const float* wo0, const float* wo1, const float* fw0, const float* fw1,
    u16* __restrict__ wall, u16* __restrict__ pfw, float* __restrict__ ball) {
  int bid = blockIdx.x;
  int tid = threadIdx.x;
  if (bid >= 1536) {
    int idx = (bid - 1536) * 256 + tid;
    if (idx < 516096) {
      int dir = idx / 258048, off = idx % 258048;
      const float* src; int soff;
      if (off < 73728) { src = dir ? wq1 : wq0; soff = off; }
      else if (off < 147456) { src = dir ? wk1 : wk0; soff = off - 73728; }
      else { src = dir ? wv1 : wv0; soff = off - 147456; }
      int o = soff / 576, k = soff % 576, t = k / 192, c = k % 192;
      wall[idx] = f2bf(src[((size_t)o * kC + c) * 3 + t]);
    } else if (idx < 516096 + 147456) {
      int i2 = idx - 516096;
      int mat = i2 / 36864, off = i2 % 36864;
      const float* src = mat == 0 ? wo0 : mat == 1 ? wo1 : mat == 2 ? fw0 : fw1;
      pfw[i2] = f2bf(src[off]);
    } else if (idx < 516096 + 147456 + 896) {
      int bi = idx - 516096 - 147456;
      int dir = bi / 448, boff = bi % 448;
      const float* s; int so;
      if (boff < 128) { s = dir ? bq1 : bq0; so = boff; }
      else if (boff < 256) { s = dir ? bk1 : bk0; so = boff - 128; }
      else { s = dir ? bv1 : bv0; so = boff - 256; }
      ball[bi] = s[so];
    }
    return;
  }
  // ---- LayerNorm part ----
  int w0 = (bid & 7) * 64;
  int n = (bid >> 3) % 96;
  int side = bid / 768;
  const float* x = side ? xr : xl;
  const float* g = side ? gr : gl;
  const float* b = side ? br : bl;
  u16* lnout = side ? lnr : lnl;
  u16* rawout = side ? rraw : lraw;
  int bb = n / kHH, h = n % kHH;
  __shared__ float tile[64][193];
  __shared__ float red[8][64];
  __shared__ float mean_s[64], rstd_s[64];
  int lane = tid & 63, wv = tid >> 6;
  for (int c = wv; c < kC; c += 4)
    tile[lane][c] = x[(((size_t)bb * kC + c) * kHH + h) * kW + w0 + lane];
  __syncthreads();
  {
    int w = tid & 63, part = tid >> 6;
    float s = 0.f, s2 = 0.f;
    const float* row = &tile[w][0];
    for (int c = part * 48; c < part * 48 + 48; ++c) {
      float v = row[c];
      s += v; s2 += v * v;
    }
    red[part][w] = s;
    red[part + 4][w] = s2;
  }
  __syncthreads();
  if (tid < 64) {
    float s = red[0][tid] + red[1][tid] + red[2][tid] + red[3][tid];
    float s2 = red[4][tid] + red[5][tid] + red[6][tid] + red[7][tid];
    float m = s * (1.f / 192.f);
    float var = s2 * (1.f / 192.f) - m * m;
    mean_s[tid] = m;
    rstd_s[tid] = rsqrtf(var + 1e-5f);
  }
  __syncthreads();
  for (int u = tid; u < 64 * 48; u += 256) {
    int w = u / 48, c4 = (u % 48) * 4;
    float mm = mean_s[w], rs = rstd_s[w];
    us4 lp, rp;
#pragma unroll
    for (int j = 0; j < 4; ++j) {
      float raw = tile[w][c4 + j];
      rp[j] = f2bf(raw);
      lp[j] = f2bf((raw - mm) * rs * g[c4 + j] + b[c4 + j]);
    }
    size_t idx = ((size_t)n * kW + w0 + w) * kC + c4;
    *reinterpret_cast<us4*>(&lnout[idx]) = lp;
    *reinterpret_cast<us4*>(&rawout[idx]) = rp;
  }
}

// ---------------- conv core: 128 l-rows x NF*32 Cout, B direct from L2 ----------------
template <int NF>
__device__ __forceinline__ void conv_core(
    const u16* __restrict__ in, const u16* __restrict__ w2,
    int n, int l0, u16* As, f32x4 (&acc)[4][NF]) {
  int tid = threadIdx.x;
  int wid = tid >> 6, lane = tid & 63;
  int wm = wid >> 1, wn = wid & 1;
  int lr = lane & 15, g = lane >> 4;
  for (int u = tid; u < 130 * 48; u += 256) {
    int row = u / 48, q = u % 48;
    int l = l0 - 1 + row;
    us4 v = {0, 0, 0, 0};
    if (l >= 0 && l < kW)
      v = *reinterpret_cast<const us4*>(in + ((size_t)n * kW + l) * kC + q * 4);
    *reinterpret_cast<us4*>(&As[row * 200 + q * 4]) = v;
  }
  __syncthreads();
  const u16* wbase = w2 + (size_t)(wn * NF * 16 + lr) * 576 + g * 8;
#pragma unroll
  for (int t = 0; t < 3; ++t) {
#pragma unroll
    for (int c0 = 0; c0 < 192; c0 += 64) {
#pragma unroll
      for (int ks = 0; ks < 2; ++ks) {
        bf16x8 a[4], b[NF];
#pragma unroll
        for (int mf = 0; mf < 4; ++mf)
          a[mf] = *reinterpret_cast<const bf16x8*>(
              &As[(wm * 64 + mf * 16 + lr + t) * 200 + c0 + ks * 32 + g * 8]);
#pragma unroll
        for (int nf = 0; nf < NF; ++nf)
          b[nf] = *reinterpret_cast<const bf16x8*>(
              wbase + (size_t)nf * 16 * 576 + t * 192 + c0 + ks * 32);
#pragma unroll
        for (int mf = 0; mf < 4; ++mf)
#pragma unroll
          for (int nf = 0; nf < NF; ++nf)
            acc[mf][nf] = __builtin_amdgcn_mfma_f32_16x16x32_bf16(a[mf], b[nf], acc[mf][nf], 0, 0, 0);
      }
    }
  }
}

// ---------------- all conv jobs + A zero-fills, one launch ----------------------------
// y 0..3: Q/K conv (dir=y>>1, which=y&1); y 4..5: V conv (dir=y-4); y 6..7: A fill (dir=y-6)
__global__ void __launch_bounds__(256) conv_all(
    const u16* __restrict__ lnl, const u16* __restrict__ lnr,
    const u16* __restrict__ lraw, const u16* __restrict__ rraw,
    const u16* __restrict__ wall, const float* __restrict__ ball,
    u16* __restrict__ Qbf, u16* __restrict__ Kbf, u16* __restrict__ Vbf,
    float* __restrict__ Abase) {
  int y = blockIdx.y;
  int tid = threadIdx.x;
  if (y >= 6) {
    int dirf = y - 6;
    int fid = blockIdx.z * 4 + blockIdx.x;
    int base_row = fid * 256;
    float* A = Abase + (size_t)dirf * 50331648;
    f32x4 z4 = {0.f, 0.f, 0.f, 0.f};
    for (int u = tid; u < 256 * 128; u += 256) {
      int lrow = u >> 7, c4 = u & 127;
      int rg = base_row + lrow;
      int nh = rg >> 9, i = rg & 511;
      int q0 = i & ~63;
      int col = c4 * 4;
      bool oob;
      if (dirf == 0) {
        int w1 = q0 + 128 > 512 ? 512 : q0 + 128;
        oob = (col < q0 || col >= w1);
      } else {
        int w0 = q0 >= 64 ? q0 - 64 : 0;
        oob = (col < w0 || col >= q0 + 64);
      }
      if (oob)
        __builtin_nontemporal_store(z4, reinterpret_cast<f32x4*>(
            A + (size_t)nh * 262144 + (size_t)i * 512 + col));
    }
    return;
  }
  int l0 = blockIdx.x * 128;
  int n = blockIdx.z;
  __shared__ __attribute__((aligned(16))) u16 As[130 * 200];
  int wid = tid >> 6, lane = tid & 63;
  int wm = wid >> 1, wn = wid & 1;
  int lr = lane & 15, g = lane >> 4;

  if (y < 4) {
    int dir = y >> 1, which = y & 1;
    const u16* in = which == 0 ? (dir ? lnr : lnl) : (dir ? lnl : lnr);
    const u16* w2 = wall + (size_t)dir * 258048 + which * 73728;
    const float* bias = ball + dir * 448 + which * 128;
    f32x4 acc[4][4] = {};
    conv_core<4>(in, w2, n, l0, As, acc);
    __syncthreads();
    u16* Ts = As;
#pragma unroll
    for (int nf = 0; nf < 4; ++nf) {
      int o = wn * 64 + nf * 16 + lr;
      float bsv = bias[o];
#pragma unroll
      for (int mf = 0; mf < 4; ++mf) {
        int lbase = wm * 64 + mf * 16 + g * 4;
#pragma unroll
        for (int rg = 0; rg < 4; ++rg)
          Ts[(lbase + rg) * 132 + o] = f2bf(acc[mf][nf][rg] + bsv);
      }
    }
    __syncthreads();
    u16* outp = (which == 0 ? Qbf : Kbf) + (size_t)dir * 6291456;
    for (int u = tid; u < 4096; u += 256) {
      int hh = u >> 11;
      int rem = u & 2047;
      int l = rem >> 4, q4 = (rem & 15) * 4;
      us4 v = *reinterpret_cast<const us4*>(&Ts[l * 132 + hh * 64 + q4]);
      *reinterpret_cast<us4*>(
          &outp[((size_t)(n * 2 + hh) * kW + l0 + l) * 64 + q4]) = v;
    }
  } else {
    int dir = y - 4;
    const u16* in = dir ? lraw : rraw;
    const u16* w2 = wall + (size_t)dir * 258048 + 147456;
    const float* bias = ball + dir * 448 + 256;
    f32x4 acc[4][6] = {};
    conv_core<6>(in, w2, n, l0, As, acc);
    u16* outp = Vbf + (size_t)dir * 9437184;
#pragma unroll
    for (int nf = 0; nf < 6; ++nf) {
      int e = nf * 16 + lr;
      float bsv = bias[wn * 96 + e];
#pragma unroll
      for (int mf = 0; mf < 4; ++mf) {
        int lb = l0 + wm * 64 + mf * 16 + g * 4;
        us4 p;
#pragma unroll
        for (int rg = 0; rg < 4; ++rg) p[rg] = f2bf(acc[mf][nf][rg] + bsv);
        *reinterpret_cast<us4*>(&outp[((size_t)(n * 2 + wn) * 96 + e) * kW + lb]) = p;
      }
    }
  }
}

// ---------------- fused attention + out-proj + FF (R9 staged version, XCD-swizzled) ---
// 1-D grid 1536; swz so each XCD gets consecutive (qb,n) blocks -> K/V halo L2 reuse.
__global__ void __launch_bounds__(256) attn_projff(
    const u16* __restrict__ Qbf, const u16* __restrict__ Kbf,
    const u16* __restrict__ Vbf, const u16* __restrict__ pfw,
    const float* __restrict__ bo0, const float* __restrict__ bo1,
    const float* __restrict__ fb0, const float* __restrict__ fb1,
    const u16* __restrict__ lraw, const u16* __restrict__ rraw,
    float* __restrict__ Abase, float* __restrict__ outbase) {
  int bid = blockIdx.x;
  int swz = (bid & 7) * 192 + (bid >> 3);  // bijective: 1536 = 8*192
  int qb = swz & 7;
  int rest = swz >> 3;
  int n = rest % 96;
  int dir = rest / 96;
  int q0 = qb * 64;
  int k_start = dir == 0 ? q0 : (q0 >= 64 ? q0 - 64 : 0);
  int k_end = dir == 0 ? (q0 + 128 <= kW ? q0 + 128 : kW) : q0 + 64;
  int kfr = (k_end - k_start) >> 4;  // 4 or 8

  // LDS pool: [Ks 128x72 | Vt 96x136] (reused as Ps 64x136, later Rs 64x200); [Os 64x200]
  __shared__ __attribute__((aligned(16))) u16 smem[35072];
  u16* Ks = smem;            // 9216
  u16* Ps = smem;            // 8704 (alias, after barrier)
  u16* Vt = smem + 9216;     // 13056
  u16* Rs = smem;            // 12800 (alias over Ks+Vt, after PV done)
  u16* Os = smem + 22272;    // 12800

  int tid = threadIdx.x;
  int wid = tid >> 6, lane = tid & 63;
  int lr = lane & 15, g = lane >> 4;

  int lo_k = q0 + wid * 16 - (dir == 0 ? 0 : 64) - k_start;
  int hi_k = q0 + wid * 16 + 15 + (dir == 0 ? 64 : 0) - k_start;
  int i = q0 + wid * 16 + lr;

#pragma unroll
  for (int h = 0; h < 2; ++h) {
    int nh = n * 2 + h;
    const u16* Q = Qbf + ((size_t)dir * 192 + nh) * kW * 64;
    const u16* K = Kbf + ((size_t)dir * 192 + nh) * kW * 64;
    const u16* V = Vbf + ((size_t)dir * 192 + nh) * 96 * kW;
    float* Aout = Abase + (size_t)dir * 50331648 + (size_t)nh * 262144;

    for (int u = tid; u < 128 * 16; u += 256) {
      int row = u >> 4, c4 = (u & 15) * 4;
      *reinterpret_cast<us4*>(&Ks[row * 72 + c4]) =
          *reinterpret_cast<const us4*>(&K[(size_t)(k_start + row) * 64 + c4]);
    }
    for (int u = tid; u < 96 * 32; u += 256) {
      int row = u >> 5, c4 = (u & 31) * 4;
      *reinterpret_cast<us4*>(&Vt[row * 136 + c4]) =
          *reinterpret_cast<const us4*>(&V[(size_t)row * kW + k_start + c4]);
    }
    const u16* Qrow = Q + (size_t)(q0 + wid * 16 + lr) * 64 + g * 8;
    bf16x8 bq0 = *reinterpret_cast<const bf16x8*>(Qrow);
    bf16x8 bq1 = *reinterpret_cast<const bf16x8*>(Qrow + 32);
    __syncthreads();

    f32x4 sT[8];
#pragma unroll
    for (int kf = 0; kf < 8; ++kf) sT[kf] = f32x4{0.f, 0.f, 0.f, 0.f};
#pragma unroll
    for (int kf = 0; kf < 8; ++kf) {
      if (kf * 16 + 15 >= lo_k && kf * 16 <= hi_k) {
        bf16x8 ak0 = *reinterpret_cast<const bf16x8*>(&Ks[(kf * 16 + lr) * 72 + g * 8]);
        sT[kf] = __builtin_amdgcn_mfma_f32_16x16x32_bf16(ak0, bq0, sT[kf], 0, 0, 0);
        bf16x8 ak1 = *reinterpret_cast<const bf16x8*>(&Ks[(kf * 16 + lr) * 72 + 32 + g * 8]);
        sT[kf] = __builtin_amdgcn_mfma_f32_16x16x32_bf16(ak1, bq1, sT[kf], 0, 0, 0);
      }
    }

    float mx = -INFINITY;
#pragma unroll
    for (int kf = 0; kf < 8; ++kf) {
#pragma unroll
      for (int r = 0; r < 4; ++r) {
        int jj = k_start + kf * 16 + g * 4 + r;
        bool valid = (jj < k_end) &&
                     (dir == 0 ? (jj >= i && jj - i <= 64) : (jj <= i && i - jj <= 64));
        float v = valid ? sT[kf][r] * 0.125f : -INFINITY;
        sT[kf][r] = v;
        mx = fmaxf(mx, v);
      }
    }
    mx = fmaxf(mx, __shfl_xor(mx, 16));
    mx = fmaxf(mx, __shfl_xor(mx, 32));
    float ssum = 0.f;
#pragma unroll
    for (int kf = 0; kf < 8; ++kf) {
#pragma unroll
      for (int r = 0; r < 4; ++r) {
        float e = __expf(sT[kf][r] - mx);
        sT[kf][r] = e;
        ssum += e;
      }
    }
    ssum += __shfl_xor(ssum, 16);
    ssum += __shfl_xor(ssum, 32);
    float inv = 1.f / ssum;

    __syncthreads();  // Ks reads done; region becomes Ps

    {
      float* arow = Aout + (size_t)i * kW + k_start;
#pragma unroll
      for (int kf = 0; kf < 8; ++kf) {
        f32x4 pv;
        us4 pb;
#pragma unroll
        for (int r = 0; r < 4; ++r) {
          float p = sT[kf][r] * inv;
          p = (p > 0.01f) ? p : 0.f;
          pv[r] = p;
          pb[r] = f2bf(p);
        }
        *reinterpret_cast<us4*>(&Ps[(wid * 16 + lr) * 136 + kf * 16 + g * 4]) = pb;
        if (kf < kfr)
          __builtin_nontemporal_store(pv, reinterpret_cast<f32x4*>(arow + kf * 16 + g * 4));
      }
    }
    __syncthreads();

    // PV with masked-chunk skip
    f32x4 oacc[6];
#pragma unroll
    for (int ef = 0; ef < 6; ++ef) oacc[ef] = f32x4{0.f, 0.f, 0.f, 0.f};
#pragma unroll
    for (int kc = 0; kc < 4; ++kc) {
      if (kc * 32 + 31 >= lo_k && kc * 32 <= hi_k) {
        bf16x8 ap = *reinterpret_cast<const bf16x8*>(&Ps[(wid * 16 + lr) * 136 + kc * 32 + g * 8]);
#pragma unroll
        for (int ef = 0; ef < 6; ++ef) {
          bf16x8 bv = *reinterpret_cast<const bf16x8*>(&Vt[(ef * 16 + lr) * 136 + kc * 32 + g * 8]);
          oacc[ef] = __builtin_amdgcn_mfma_f32_16x16x32_bf16(ap, bv, oacc[ef], 0, 0, 0);
        }
      }
    }
    // O tile into LDS (cols h*96 .. h*96+95)
#pragma unroll
    for (int ef = 0; ef < 6; ++ef) {
      int e = h * 96 + ef * 16 + lr;
#pragma unroll
      for (int r = 0; r < 4; ++r)
        Os[(wid * 16 + g * 4 + r) * 200 + e] = f2bf(oacc[ef][r]);
    }
    __syncthreads();  // Ps/Vt reads + Os writes done
  }

  // ---- stage residual into Rs (over the K/V region) ----
  const u16* resbf = dir ? rraw : lraw;
  for (int u = tid; u < 64 * 48; u += 256) {
    int row = u / 48, q = u % 48;
    *reinterpret_cast<us4*>(&Rs[row * 200 + q * 4]) =
        *reinterpret_cast<const us4*>(&resbf[((size_t)n * kW + q0 + row) * kC + q * 4]);
  }

  const u16* wo2 = pfw + (dir ? 36864 : 0);
  const u16* fw2 = pfw + 73728 + (dir ? 36864 : 0);
  const float* bo_ = dir ? bo1 : bo0;
  const float* fb_ = dir ? fb1 : fb0;
  float* outb = outbase + (size_t)dir * 9437184;
  int bb = n / kHH, hh_ = n % kHH;

  int wm = wid >> 1, wn = wid & 1;
  const u16* wobase = wo2 + (size_t)(wn * 96 + lr) * kC + g * 8;
  const u16* fwbase = fw2 + (size_t)(wn * 96 + lr) * kC + g * 8;

  // ---- proj phase ----
  f32x4 accp[2][6] = {};
#pragma unroll
  for (int c0 = 0; c0 < 192; c0 += 64) {
#pragma unroll
    for (int ks = 0; ks < 2; ++ks) {
      bf16x8 a[2], b[6];
#pragma unroll
      for (int m2 = 0; m2 < 2; ++m2)
        a[m2] = *reinterpret_cast<const bf16x8*>(
            &Os[(wm * 32 + m2 * 16 + lr) * 200 + c0 + ks * 32 + g * 8]);
#pragma unroll
      for (int nf = 0; nf < 6; ++nf)
        b[nf] = *reinterpret_cast<const bf16x8*>(
            wobase + (size_t)nf * 16 * kC + c0 + ks * 32);
#pragma unroll
      for (int m2 = 0; m2 < 2; ++m2)
#pragma unroll
        for (int nf = 0; nf < 6; ++nf)
          accp[m2][nf] = __builtin_amdgcn_mfma_f32_16x16x32_bf16(a[m2], b[nf], accp[m2][nf], 0, 0, 0);
    }
  }
  __syncthreads();  // proj reads of Os done; Rs writes visible
#pragma unroll
  for (int nf = 0; nf < 6; ++nf) {
    int o = wn * 96 + nf * 16 + lr;
    float bv = bo_[o];
#pragma unroll
    for (int m2 = 0; m2 < 2; ++m2) {
#pragma unroll
      for (int r = 0; r < 4; ++r) {
        int l = wm * 32 + m2 * 16 + g * 4 + r;
        float v = accp[m2][nf][r] + bv + bf2f(Rs[l * 200 + o]);
        accp[m2][nf][r] = v;
        Os[l * 200 + o] = f2bf(v);
      }
    }
  }
  __syncthreads();

  // ---- ff phase ----
  f32x4 accf[2][6] = {};
#pragma unroll
  for (int c0 = 0; c0 < 192; c0 += 64) {
#pragma unroll
    for (int ks = 0; ks < 2; ++ks) {
      bf16x8 a[2], b[6];
#pragma unroll
      for (int m2 = 0; m2 < 2; ++m2)
        a[m2] = *reinterpret_cast<const bf16x8*>(
            &Os[(wm * 32 + m2 * 16 + lr) * 200 + c0 + ks * 32 + g * 8]);
#pragma unroll
      for (int nf = 0; nf < 6; ++nf)
        b[nf] = *reinterpret_cast<const bf16x8*>(
            fwbase + (size_t)nf * 16 * kC + c0 + ks * 32);
#pragma unroll
      for (int m2 = 0; m2 < 2; ++m2)
#pragma unroll
        for (int nf = 0; nf < 6; ++nf)
          accf[m2][nf] = __builtin_amdgcn_mfma_f32_16x16x32_bf16(a[m2], b[nf], accf[m2][nf], 0, 0, 0);
    }
  }
#pragma unroll
  for (int nf = 0; nf < 6; ++nf) {
    int o = wn * 96 + nf * 16 + lr;
    float bv = fb_[o];
#pragma unroll
    for (int m2 = 0; m2 < 2; ++m2) {
      f32x4 ov;
#pragma unroll
      for (int r = 0; r < 4; ++r)
        ov[r] = accf[m2][nf][r] + bv + accp[m2][nf][r];
      int l = q0 + wm * 32 + m2 * 16 + g * 4;
      *reinterpret_cast<f32x4*>(&outb[(((size_t)bb * kC + o) * kHH + hh_) * kW + l]) = ov;
    }
  }
}

extern "C" void kernel_launch(void* const* d_in, const int* in_sizes, int n_in,
                              void* d_out, int out_size, void* d_ws, size_t ws_size,
                              hipStream_t stream) {
  const float* l = (const float*)d_in[0];
  const float* r = (const float*)d_in[1];
  float* out = (float*)d_out;
  float* ws = (float*)d_ws;

  u16* lnl_bf  = (u16*)(ws + 0);          // [96][512][192] bf16
  u16* lnr_bf  = (u16*)(ws + 4718592);
  u16* lraw_bf = (u16*)(ws + 9437184);
  u16* rraw_bf = (u16*)(ws + 14155776);
  u16* wall    = (u16*)(ws + 18874368);   // 516096 u16
  float* ball  = ws + 19136512;           // 896 f
  u16* Qbf     = (u16*)(ws + 19137536);   // [2][192][512][64] bf16
  u16* Kbf     = (u16*)(ws + 25428992);
  u16* Vbf     = (u16*)(ws + 31720448);   // [2][192][96][512] bf16
  u16* pfw     = (u16*)(ws + 50594816);   // 147456 u16: wo0,wo1,fw0,fw1

  float* A0 = out + (size_t)18874368;     // dir0 A (dir1 = A0 + 50331648)

  int wp_items = 516096 + 147456 + 896;
  int wp_blocks = (wp_items + 255) / 256;
  prep_kernel<<<1536 + wp_blocks, 256, 0, stream>>>(
      l, r, (const float*)d_in[2], (const float*)d_in[3],
      (const float*)d_in[4], (const float*)d_in[5],
      lnl_bf, lraw_bf, lnr_bf, rraw_bf,
      (const float*)d_in[6], (const float*)d_in[8], (const float*)d_in[10],
      (const float*)d_in[14], (const float*)d_in[16], (const float*)d_in[18],
      (const float*)d_in[7], (const float*)d_in[9], (const float*)d_in[11],
      (const float*)d_in[15], (const float*)d_in[17], (const float*)d_in[19],
      (const float*)d_in[12], (const float*)d_in[20],
      (const float*)d_in[22], (const float*)d_in[24],
      wall, pfw, ball);

  conv_all<<<dim3(4, 8, 96), 256, 0, stream>>>(
      lnl_bf, lnr_bf, lraw_bf, rraw_bf, wall, ball, Qbf, Kbf, Vbf, A0);

  attn_projff<<<1536, 256, 0, stream>>>(
      Qbf, Kbf, Vbf, pfw,
      (const float*)d_in[13], (const float*)d_in[21],
      (const float*)d_in[23], (const float*)d_in[25],
      lraw_bf, rraw_bf, A0, out);
}

// Round 12
// 348.308 us; speedup vs baseline: 1.1690x; 1.1690x over previous
//
#include <hip/hip_runtime.h>
#include <cstddef>
#include <cstdint>

constexpr int kC = 192;    // channels
constexpr int kW = 512;    // sequence length
constexpr int kHH = 48;    // H

typedef unsigned short u16;
typedef __attribute__((ext_vector_type(8))) short bf16x8;
typedef __attribute__((ext_vector_type(4))) float f32x4;
typedef __attribute__((ext_vector_type(4))) unsigned short us4;

__device__ inline u16 f2bf(float f) {
  union { float f; uint32_t u; } v; v.f = f;
  uint32_t r = v.u + 0x7FFF + ((v.u >> 16) & 1);  // RNE
  return (u16)(r >> 16);
}
__device__ inline float bf2f(u16 u) {
  return __uint_as_float(((uint32_t)u) << 16);
}

// ---------------- prep: LayerNorm (blocks 0..1535) + weight conversion (rest) ---------
__global__ void __launch_bounds__(256) prep_kernel(
    const float* __restrict__ xl, const float* __restrict__ xr,
    const float* __restrict__ gl, const float* __restrict__ bl,
    const float* __restrict__ gr, const float* __restrict__ br,
    u16* __restrict__ lnl, u16* __restrict__ lraw,
    u16* __restrict__ lnr, u16* __restrict__ rraw,
    const float* wq0, const float* wk0, const float* wv0,
    const float* wq1, const float* wk1, const float* wv1,
    const float* bq0, const float* bk0, const float* bv0,
    const float* bq1, const float* bk1, const float* bv1,
    const float* wo0, const float* wo1, const float* fw0, const float* fw1,
    u16* __restrict__ wall, u16* __restrict__ pfw, float* __restrict__ ball) {
  int bid = blockIdx.x;
  int tid = threadIdx.x;
  if (bid >= 1536) {
    int idx = (bid - 1536) * 256 + tid;
    if (idx < 516096) {
      int dir = idx / 258048, off = idx % 258048;
      const float* src; int soff;
      if (off < 73728) { src = dir ? wq1 : wq0; soff = off; }
      else if (off < 147456) { src = dir ? wk1 : wk0; soff = off - 73728; }
      else { src = dir ? wv1 : wv0; soff = off - 147456; }
      int o = soff / 576, k = soff % 576, t = k / 192, c = k % 192;
      wall[idx] = f2bf(src[((size_t)o * kC + c) * 3 + t]);
    } else if (idx < 516096 + 147456) {
      int i2 = idx - 516096;
      int mat = i2 / 36864, off = i2 % 36864;
      const float* src = mat == 0 ? wo0 : mat == 1 ? wo1 : mat == 2 ? fw0 : fw1;
      pfw[i2] = f2bf(src[off]);
    } else if (idx < 516096 + 147456 + 896) {
      int bi = idx - 516096 - 147456;
      int dir = bi / 448, boff = bi % 448;
      const float* s; int so;
      if (boff < 128) { s = dir ? bq1 : bq0; so = boff; }
      else if (boff < 256) { s = dir ? bk1 : bk0; so = boff - 128; }
      else { s = dir ? bv1 : bv0; so = boff - 256; }
      ball[bi] = s[so];
    }
    return;
  }
  // ---- LayerNorm part ----
  int w0 = (bid & 7) * 64;
  int n = (bid >> 3) % 96;
  int side = bid / 768;
  const float* x = side ? xr : xl;
  const float* g = side ? gr : gl;
  const float* b = side ? br : bl;
  u16* lnout = side ? lnr : lnl;
  u16* rawout = side ? rraw : lraw;
  int bb = n / kHH, h = n % kHH;
  __shared__ float tile[64][193];
  __shared__ float red[8][64];
  __shared__ float mean_s[64], rstd_s[64];
  int lane = tid & 63, wv = tid >> 6;
  for (int c = wv; c < kC; c += 4)
    tile[lane][c] = x[(((size_t)bb * kC + c) * kHH + h) * kW + w0 + lane];
  __syncthreads();
  {
    int w = tid & 63, part = tid >> 6;
    float s = 0.f, s2 = 0.f;
    const float* row = &tile[w][0];
    for (int c = part * 48; c < part * 48 + 48; ++c) {
      float v = row[c];
      s += v; s2 += v * v;
    }
    red[part][w] = s;
    red[part + 4][w] = s2;
  }
  __syncthreads();
  if (tid < 64) {
    float s = red[0][tid] + red[1][tid] + red[2][tid] + red[3][tid];
    float s2 = red[4][tid] + red[5][tid] + red[6][tid] + red[7][tid];
    float m = s * (1.f / 192.f);
    float var = s2 * (1.f / 192.f) - m * m;
    mean_s[tid] = m;
    rstd_s[tid] = rsqrtf(var + 1e-5f);
  }
  __syncthreads();
  for (int u = tid; u < 64 * 48; u += 256) {
    int w = u / 48, c4 = (u % 48) * 4;
    float mm = mean_s[w], rs = rstd_s[w];
    us4 lp, rp;
#pragma unroll
    for (int j = 0; j < 4; ++j) {
      float raw = tile[w][c4 + j];
      rp[j] = f2bf(raw);
      lp[j] = f2bf((raw - mm) * rs * g[c4 + j] + b[c4 + j]);
    }
    size_t idx = ((size_t)n * kW + w0 + w) * kC + c4;
    *reinterpret_cast<us4*>(&lnout[idx]) = lp;
    *reinterpret_cast<us4*>(&rawout[idx]) = rp;
  }
}

// ---------------- conv core: 128 l-rows x NF*32 Cout, B direct from L2 ----------------
template <int NF>
__device__ __forceinline__ void conv_core(
    const u16* __restrict__ in, const u16* __restrict__ w2,
    int n, int l0, u16* As, f32x4 (&acc)[4][NF]) {
  int tid = threadIdx.x;
  int wid = tid >> 6, lane = tid & 63;
  int wm = wid >> 1, wn = wid & 1;
  int lr = lane & 15, g = lane >> 4;
  for (int u = tid; u < 130 * 48; u += 256) {
    int row = u / 48, q = u % 48;
    int l = l0 - 1 + row;
    us4 v = {0, 0, 0, 0};
    if (l >= 0 && l < kW)
      v = *reinterpret_cast<const us4*>(in + ((size_t)n * kW + l) * kC + q * 4);
    *reinterpret_cast<us4*>(&As[row * 200 + q * 4]) = v;
  }
  __syncthreads();
  const u16* wbase = w2 + (size_t)(wn * NF * 16 + lr) * 576 + g * 8;
#pragma unroll
  for (int t = 0; t < 3; ++t) {
#pragma unroll
    for (int c0 = 0; c0 < 192; c0 += 64) {
#pragma unroll
      for (int ks = 0; ks < 2; ++ks) {
        bf16x8 a[4], b[NF];
#pragma unroll
        for (int mf = 0; mf < 4; ++mf)
          a[mf] = *reinterpret_cast<const bf16x8*>(
              &As[(wm * 64 + mf * 16 + lr + t) * 200 + c0 + ks * 32 + g * 8]);
#pragma unroll
        for (int nf = 0; nf < NF; ++nf)
          b[nf] = *reinterpret_cast<const bf16x8*>(
              wbase + (size_t)nf * 16 * 576 + t * 192 + c0 + ks * 32);
#pragma unroll
        for (int mf = 0; mf < 4; ++mf)
#pragma unroll
          for (int nf = 0; nf < NF; ++nf)
            acc[mf][nf] = __builtin_amdgcn_mfma_f32_16x16x32_bf16(a[mf], b[nf], acc[mf][nf], 0, 0, 0);
      }
    }
  }
}

// ---------------- conv Q/K (Cout=128) + dir0 A zero-fill (y==4) -----------------------
__global__ void __launch_bounds__(256) conv_qk(
    const u16* __restrict__ lnl, const u16* __restrict__ lnr,
    const u16* __restrict__ wall, const float* __restrict__ ball,
    u16* __restrict__ Qbf, u16* __restrict__ Kbf, float* __restrict__ A0) {
  if (blockIdx.y == 4) {
    int fid = blockIdx.z * 4 + blockIdx.x;
    int base_row = fid * 256;
    f32x4 z4 = {0.f, 0.f, 0.f, 0.f};
    for (int u = threadIdx.x; u < 256 * 128; u += 256) {
      int lrow = u >> 7, c4 = u & 127;
      int rg = base_row + lrow;
      int nh = rg >> 9, i = rg & 511;
      int q0 = i & ~63;
      int w1 = q0 + 128 > 512 ? 512 : q0 + 128;
      int col = c4 * 4;
      if (col < q0 || col >= w1)
        __builtin_nontemporal_store(z4, reinterpret_cast<f32x4*>(
            A0 + (size_t)nh * 262144 + (size_t)i * 512 + col));
    }
    return;
  }
  int l0 = blockIdx.x * 128;
  int jid = blockIdx.y;
  int n = blockIdx.z;
  int dir = jid >> 1, which = jid & 1;
  const u16* in = which == 0 ? (dir ? lnr : lnl) : (dir ? lnl : lnr);
  const u16* w2 = wall + (size_t)dir * 258048 + which * 73728;
  const float* bias = ball + dir * 448 + which * 128;

  __shared__ __attribute__((aligned(16))) u16 As[130 * 200];
  f32x4 acc[4][4] = {};
  conv_core<4>(in, w2, n, l0, As, acc);

  int tid = threadIdx.x;
  int wid = tid >> 6, lane = tid & 63;
  int wm = wid >> 1, wn = wid & 1;
  int lr = lane & 15, g = lane >> 4;
  __syncthreads();
  u16* Ts = As;
#pragma unroll
  for (int nf = 0; nf < 4; ++nf) {
    int o = wn * 64 + nf * 16 + lr;
    float bsv = bias[o];
#pragma unroll
    for (int mf = 0; mf < 4; ++mf) {
      int lbase = wm * 64 + mf * 16 + g * 4;
#pragma unroll
      for (int rg = 0; rg < 4; ++rg)
        Ts[(lbase + rg) * 132 + o] = f2bf(acc[mf][nf][rg] + bsv);
    }
  }
  __syncthreads();
  u16* outp = (which == 0 ? Qbf : Kbf) + (size_t)dir * 6291456;
  for (int u = tid; u < 4096; u += 256) {
    int hh = u >> 11;
    int rem = u & 2047;
    int l = rem >> 4, q4 = (rem & 15) * 4;
    us4 v = *reinterpret_cast<const us4*>(&Ts[l * 132 + hh * 64 + q4]);
    *reinterpret_cast<us4*>(
        &outp[((size_t)(n * 2 + hh) * kW + l0 + l) * 64 + q4]) = v;
  }
}

// ---------------- conv V (Cout=192) + dir1 A zero-fill (y==2) -------------------------
__global__ void __launch_bounds__(256) conv_v(
    const u16* __restrict__ lraw, const u16* __restrict__ rraw,
    const u16* __restrict__ wall, const float* __restrict__ ball,
    u16* __restrict__ Vbf, float* __restrict__ A1) {
  if (blockIdx.y == 2) {
    int fid = blockIdx.z * 4 + blockIdx.x;
    int base_row = fid * 256;
    f32x4 z4 = {0.f, 0.f, 0.f, 0.f};
    for (int u = threadIdx.x; u < 256 * 128; u += 256) {
      int lrow = u >> 7, c4 = u & 127;
      int rg = base_row + lrow;
      int nh = rg >> 9, i = rg & 511;
      int q0 = i & ~63;
      int w0 = q0 >= 64 ? q0 - 64 : 0;
      int col = c4 * 4;
      if (col < w0 || col >= q0 + 64)
        __builtin_nontemporal_store(z4, reinterpret_cast<f32x4*>(
            A1 + (size_t)nh * 262144 + (size_t)i * 512 + col));
    }
    return;
  }
  int l0 = blockIdx.x * 128;
  int dir = blockIdx.y;
  int n = blockIdx.z;
  const u16* in = dir ? lraw : rraw;
  const u16* w2 = wall + (size_t)dir * 258048 + 147456;
  const float* bias = ball + dir * 448 + 256;

  __shared__ __attribute__((aligned(16))) u16 As[130 * 200];
  f32x4 acc[4][6] = {};
  conv_core<6>(in, w2, n, l0, As, acc);

  int tid = threadIdx.x;
  int wid = tid >> 6, lane = tid & 63;
  int wm = wid >> 1, wn = wid & 1;
  int lr = lane & 15, g = lane >> 4;
  u16* outp = Vbf + (size_t)dir * 9437184;
#pragma unroll
  for (int nf = 0; nf < 6; ++nf) {
    int e = nf * 16 + lr;
    float bsv = bias[wn * 96 + e];
#pragma unroll
    for (int mf = 0; mf < 4; ++mf) {
      int lb = l0 + wm * 64 + mf * 16 + g * 4;
      us4 p;
#pragma unroll
      for (int rg = 0; rg < 4; ++rg) p[rg] = f2bf(acc[mf][nf][rg] + bsv);
      *reinterpret_cast<us4*>(&outp[((size_t)(n * 2 + wn) * 96 + e) * kW + lb]) = p;
    }
  }
}

// ---------------- fused attention + out-proj + FF (K/V staged; R9 structure) ----------
__global__ void __launch_bounds__(256) attn_projff(
    const u16* __restrict__ Qbf, const u16* __restrict__ Kbf,
    const u16* __restrict__ Vbf, const u16* __restrict__ pfw,
    const float* __restrict__ bo0, const float* __restrict__ bo1,
    const float* __restrict__ fb0, const float* __restrict__ fb1,
    const u16* __restrict__ lraw, const u16* __restrict__ rraw,
    float* __restrict__ Abase, float* __restrict__ outbase) {
  int qb = blockIdx.x;
  int n = blockIdx.y;
  int dir = blockIdx.z;
  int q0 = qb * 64;
  int k_start = dir == 0 ? q0 : (q0 >= 64 ? q0 - 64 : 0);
  int k_end = dir == 0 ? (q0 + 128 <= kW ? q0 + 128 : kW) : q0 + 64;
  int kfr = (k_end - k_start) >> 4;  // 4 or 8

  // LDS pool: [Ks 128x72 | Vt 96x136] (reused as Ps 64x136, later Rs 64x200); [Os 64x200]
  __shared__ __attribute__((aligned(16))) u16 smem[35072];
  u16* Ks = smem;            // 9216
  u16* Ps = smem;            // 8704 (alias, after barrier)
  u16* Vt = smem + 9216;     // 13056
  u16* Rs = smem;            // 12800 (alias over Ks+Vt, after PV done)
  u16* Os = smem + 22272;    // 12800

  int tid = threadIdx.x;
  int wid = tid >> 6, lane = tid & 63;
  int lr = lane & 15, g = lane >> 4;

  int lo_k = q0 + wid * 16 - (dir == 0 ? 0 : 64) - k_start;
  int hi_k = q0 + wid * 16 + 15 + (dir == 0 ? 64 : 0) - k_start;
  int i = q0 + wid * 16 + lr;

#pragma unroll
  for (int h = 0; h < 2; ++h) {
    int nh = n * 2 + h;
    const u16* Q = Qbf + ((size_t)dir * 192 + nh) * kW * 64;
    const u16* K = Kbf + ((size_t)dir * 192 + nh) * kW * 64;
    const u16* V = Vbf + ((size_t)dir * 192 + nh) * 96 * kW;
    float* Aout = Abase + (size_t)dir * 50331648 + (size_t)nh * 262144;

    for (int u = tid; u < 128 * 16; u += 256) {
      int row = u >> 4, c4 = (u & 15) * 4;
      *reinterpret_cast<us4*>(&Ks[row * 72 + c4]) =
          *reinterpret_cast<const us4*>(&K[(size_t)(k_start + row) * 64 + c4]);
    }
    for (int u = tid; u < 96 * 32; u += 256) {
      int row = u >> 5, c4 = (u & 31) * 4;
      *reinterpret_cast<us4*>(&Vt[row * 136 + c4]) =
          *reinterpret_cast<const us4*>(&V[(size_t)row * kW + k_start + c4]);
    }
    const u16* Qrow = Q + (size_t)(q0 + wid * 16 + lr) * 64 + g * 8;
    bf16x8 bq0 = *reinterpret_cast<const bf16x8*>(Qrow);
    bf16x8 bq1 = *reinterpret_cast<const bf16x8*>(Qrow + 32);
    __syncthreads();

    f32x4 sT[8];
#pragma unroll
    for (int kf = 0; kf < 8; ++kf) sT[kf] = f32x4{0.f, 0.f, 0.f, 0.f};
#pragma unroll
    for (int kf = 0; kf < 8; ++kf) {
      if (kf * 16 + 15 >= lo_k && kf * 16 <= hi_k) {
        bf16x8 ak0 = *reinterpret_cast<const bf16x8*>(&Ks[(kf * 16 + lr) * 72 + g * 8]);
        sT[kf] = __builtin_amdgcn_mfma_f32_16x16x32_bf16(ak0, bq0, sT[kf], 0, 0, 0);
        bf16x8 ak1 = *reinterpret_cast<const bf16x8*>(&Ks[(kf * 16 + lr) * 72 + 32 + g * 8]);
        sT[kf] = __builtin_amdgcn_mfma_f32_16x16x32_bf16(ak1, bq1, sT[kf], 0, 0, 0);
      }
    }

    float mx = -INFINITY;
#pragma unroll
    for (int kf = 0; kf < 8; ++kf) {
#pragma unroll
      for (int r = 0; r < 4; ++r) {
        int jj = k_start + kf * 16 + g * 4 + r;
        bool valid = (jj < k_end) &&
                     (dir == 0 ? (jj >= i && jj - i <= 64) : (jj <= i && i - jj <= 64));
        float v = valid ? sT[kf][r] * 0.125f : -INFINITY;
        sT[kf][r] = v;
        mx = fmaxf(mx, v);
      }
    }
    mx = fmaxf(mx, __shfl_xor(mx, 16));
    mx = fmaxf(mx, __shfl_xor(mx, 32));
    float ssum = 0.f;
#pragma unroll
    for (int kf = 0; kf < 8; ++kf) {
#pragma unroll
      for (int r = 0; r < 4; ++r) {
        float e = __expf(sT[kf][r] - mx);
        sT[kf][r] = e;
        ssum += e;
      }
    }
    ssum += __shfl_xor(ssum, 16);
    ssum += __shfl_xor(ssum, 32);
    float inv = 1.f / ssum;

    __syncthreads();  // Ks reads done; region becomes Ps

    {
      float* arow = Aout + (size_t)i * kW + k_start;
#pragma unroll
      for (int kf = 0; kf < 8; ++kf) {
        f32x4 pv;
        us4 pb;
#pragma unroll
        for (int r = 0; r < 4; ++r) {
          float p = sT[kf][r] * inv;
          p = (p > 0.01f) ? p : 0.f;
          pv[r] = p;
          pb[r] = f2bf(p);
        }
        *reinterpret_cast<us4*>(&Ps[(wid * 16 + lr) * 136 + kf * 16 + g * 4]) = pb;
        if (kf < kfr)
          __builtin_nontemporal_store(pv, reinterpret_cast<f32x4*>(arow + kf * 16 + g * 4));
      }
    }
    __syncthreads();

    // PV with masked-chunk skip
    f32x4 oacc[6];
#pragma unroll
    for (int ef = 0; ef < 6; ++ef) oacc[ef] = f32x4{0.f, 0.f, 0.f, 0.f};
#pragma unroll
    for (int kc = 0; kc < 4; ++kc) {
      if (kc * 32 + 31 >= lo_k && kc * 32 <= hi_k) {
        bf16x8 ap = *reinterpret_cast<const bf16x8*>(&Ps[(wid * 16 + lr) * 136 + kc * 32 + g * 8]);
#pragma unroll
        for (int ef = 0; ef < 6; ++ef) {
          bf16x8 bv = *reinterpret_cast<const bf16x8*>(&Vt[(ef * 16 + lr) * 136 + kc * 32 + g * 8]);
          oacc[ef] = __builtin_amdgcn_mfma_f32_16x16x32_bf16(ap, bv, oacc[ef], 0, 0, 0);
        }
      }
    }
    // O tile into LDS (cols h*96 .. h*96+95)
#pragma unroll
    for (int ef = 0; ef < 6; ++ef) {
      int e = h * 96 + ef * 16 + lr;
#pragma unroll
      for (int r = 0; r < 4; ++r)
        Os[(wid * 16 + g * 4 + r) * 200 + e] = f2bf(oacc[ef][r]);
    }
    __syncthreads();  // Ps/Vt reads + Os writes done
  }

  // ---- stage residual into Rs (over the K/V region) ----
  const u16* resbf = dir ? rraw : lraw;
  for (int u = tid; u < 64 * 48; u += 256) {
    int row = u / 48, q = u % 48;
    *reinterpret_cast<us4*>(&Rs[row * 200 + q * 4]) =
        *reinterpret_cast<const us4*>(&resbf[((size_t)n * kW + q0 + row) * kC + q * 4]);
  }

  const u16* wo2 = pfw + (dir ? 36864 : 0);
  const u16* fw2 = pfw + 73728 + (dir ? 36864 : 0);
  const float* bo_ = dir ? bo1 : bo0;
  const float* fb_ = dir ? fb1 : fb0;
  float* outb = outbase + (size_t)dir * 9437184;
  int bb = n / kHH, hh_ = n % kHH;

  int wm = wid >> 1, wn = wid & 1;
  const u16* wobase = wo2 + (size_t)(wn * 96 + lr) * kC + g * 8;
  const u16* fwbase = fw2 + (size_t)(wn * 96 + lr) * kC + g * 8;

  // ---- proj phase ----
  f32x4 accp[2][6] = {};
#pragma unroll
  for (int c0 = 0; c0 < 192; c0 += 64) {
#pragma unroll
    for (int ks = 0; ks < 2; ++ks) {
      bf16x8 a[2], b[6];
#pragma unroll
      for (int m2 = 0; m2 < 2; ++m2)
        a[m2] = *reinterpret_cast<const bf16x8*>(
            &Os[(wm * 32 + m2 * 16 + lr) * 200 + c0 + ks * 32 + g * 8]);
#pragma unroll
      for (int nf = 0; nf < 6; ++nf)
        b[nf] = *reinterpret_cast<const bf16x8*>(
            wobase + (size_t)nf * 16 * kC + c0 + ks * 32);
#pragma unroll
      for (int m2 = 0; m2 < 2; ++m2)
#pragma unroll
        for (int nf = 0; nf < 6; ++nf)
          accp[m2][nf] = __builtin_amdgcn_mfma_f32_16x16x32_bf16(a[m2], b[nf], accp[m2][nf], 0, 0, 0);
    }
  }
  __syncthreads();  // proj reads of Os done; Rs writes visible
#pragma unroll
  for (int nf = 0; nf < 6; ++nf) {
    int o = wn * 96 + nf * 16 + lr;
    float bv = bo_[o];
#pragma unroll
    for (int m2 = 0; m2 < 2; ++m2) {
#pragma unroll
      for (int r = 0; r < 4; ++r) {
        int l = wm * 32 + m2 * 16 + g * 4 + r;
        float v = accp[m2][nf][r] + bv + bf2f(Rs[l * 200 + o]);
        accp[m2][nf][r] = v;
        Os[l * 200 + o] = f2bf(v);
      }
    }
  }
  __syncthreads();

  // ---- ff phase ----
  f32x4 accf[2][6] = {};
#pragma unroll
  for (int c0 = 0; c0 < 192; c0 += 64) {
#pragma unroll
    for (int ks = 0; ks < 2; ++ks) {
      bf16x8 a[2], b[6];
#pragma unroll
      for (int m2 = 0; m2 < 2; ++m2)
        a[m2] = *reinterpret_cast<const bf16x8*>(
            &Os[(wm * 32 + m2 * 16 + lr) * 200 + c0 + ks * 32 + g * 8]);
#pragma unroll
      for (int nf = 0; nf < 6; ++nf)
        b[nf] = *reinterpret_cast<const bf16x8*>(
            fwbase + (size_t)nf * 16 * kC + c0 + ks * 32);
#pragma unroll
      for (int m2 = 0; m2 < 2; ++m2)
#pragma unroll
        for (int nf = 0; nf < 6; ++nf)
          accf[m2][nf] = __builtin_amdgcn_mfma_f32_16x16x32_bf16(a[m2], b[nf], accf[m2][nf], 0, 0, 0);
    }
  }
#pragma unroll
  for (int nf = 0; nf < 6; ++nf) {
    int o = wn * 96 + nf * 16 + lr;
    float bv = fb_[o];
#pragma unroll
    for (int m2 = 0; m2 < 2; ++m2) {
      f32x4 ov;
#pragma unroll
      for (int r = 0; r < 4; ++r)
        ov[r] = accf[m2][nf][r] + bv + accp[m2][nf][r];
      int l = q0 + wm * 32 + m2 * 16 + g * 4;
      *reinterpret_cast<f32x4*>(&outb[(((size_t)bb * kC + o) * kHH + hh_) * kW + l]) = ov;
    }
  }
}

extern "C" void kernel_launch(void* const* d_in, const int* in_sizes, int n_in,
                              void* d_out, int out_size, void* d_ws, size_t ws_size,
                              hipStream_t stream) {
  const float* l = (const float*)d_in[0];
  const float* r = (const float*)d_in[1];
  float* out = (float*)d_out;
  float* ws = (float*)d_ws;

  u16* lnl_bf  = (u16*)(ws + 0);          // [96][512][192] bf16
  u16* lnr_bf  = (u16*)(ws + 4718592);
  u16* lraw_bf = (u16*)(ws + 9437184);
  u16* rraw_bf = (u16*)(ws + 14155776);
  u16* wall    = (u16*)(ws + 18874368);   // 516096 u16
  float* ball  = ws + 19136512;           // 896 f
  u16* Qbf     = (u16*)(ws + 19137536);   // [2][192][512][64] bf16
  u16* Kbf     = (u16*)(ws + 25428992);
  u16* Vbf     = (u16*)(ws + 31720448);   // [2][192][96][512] bf16
  u16* pfw     = (u16*)(ws + 50594816);   // 147456 u16: wo0,wo1,fw0,fw1

  float* A0 = out + (size_t)18874368;     // dir0 A
  float* A1 = out + (size_t)69206016;     // dir1 A

  int wp_items = 516096 + 147456 + 896;
  int wp_blocks = (wp_items + 255) / 256;
  prep_kernel<<<1536 + wp_blocks, 256, 0, stream>>>(
      l, r, (const float*)d_in[2], (const float*)d_in[3],
      (const float*)d_in[4], (const float*)d_in[5],
      lnl_bf, lraw_bf, lnr_bf, rraw_bf,
      (const float*)d_in[6], (const float*)d_in[8], (const float*)d_in[10],
      (const float*)d_in[14], (const float*)d_in[16], (const float*)d_in[18],
      (const float*)d_in[7], (const float*)d_in[9], (const float*)d_in[11],
      (const float*)d_in[15], (const float*)d_in[17], (const float*)d_in[19],
      (const float*)d_in[12], (const float*)d_in[20],
      (const float*)d_in[22], (const float*)d_in[24],
      wall, pfw, ball);

  conv_qk<<<dim3(4, 5, 96), 256, 0, stream>>>(
      lnl_bf, lnr_bf, wall, ball, Qbf, Kbf, A0);
  conv_v<<<dim3(4, 3, 96), 256, 0, stream>>>(
      lraw_bf, rraw_bf, wall, ball, Vbf, A1);

  attn_projff<<<dim3(8, 96, 2), 256, 0, stream>>>(
      Qbf, Kbf, Vbf, pfw,
      (const float*)d_in[13], (const float*)d_in[21],
      (const float*)d_in[23], (const float*)d_in[25],
      lraw_bf, rraw_bf, A0, out);
}